// Round 1
// baseline (177.076 us; speedup 1.0000x reference)
//
#include <hip/hip_runtime.h>

// Problem constants (from reference): B=64, T=128, D=1024, H=512
#define B_ 64
#define T_ 128
#define D_ 1024
#define H_ 512

// ---------------------------------------------------------------------------
// Analytic reduction (verified in prior rounds, absmax == 0):
//   loss_row(b,j) = LSE_p(xs[b,p] for p in [j+2, len_b)) - xs[b, j+2]
// because hs, fc_b, W_ih/W_hh/b_* all cancel in lse - logits[..., 0].
// Only xs[b,t] = dot(x[b,t,:], fc_w[H:]) is needed.
//
// This round: fuse {xs, loss, final} into ONE kernel via last-block-per-batch
// handoff (device-scope atomics + __threadfence, safe across non-coherent
// XCD L2s), preceded by a tiny counter-init kernel. 3 dispatches -> 2;
// removes two inter-kernel drains and overlaps per-batch LSE with the xs
// GEMV tail. The timed region is dominated by harness 256-MiB poison fills
// (~44 us each @ 76% HBM peak) which kernel_launch cannot influence; this
// targets the ~15 us controllable slice.
// ---------------------------------------------------------------------------

// Zero the B_ per-batch completion counters + 1 grid "done" counter.
__global__ __launch_bounds__(128) void init_kernel(int* __restrict__ cnt) {
    if (threadIdx.x < B_ + 1) cnt[threadIdx.x] = 0;
}

__global__ __launch_bounds__(256) void fused_kernel(
        const float* __restrict__ x, const int* __restrict__ mask,
        const float* __restrict__ fc_w, float* __restrict__ xs,
        float* __restrict__ ploss, int* __restrict__ pcnt,
        int* __restrict__ cnt, float* __restrict__ out)
{
    // ---- phase 1: xs[row] = dot(x[row,:], w_x); 4 rows (waves) per block --
    const float* wx = fc_w + H_;
    const int wave = threadIdx.x >> 6;
    const int lane = threadIdx.x & 63;
    const int row  = blockIdx.x * 4 + wave;           // row in [0, B*T)
    const int b    = blockIdx.x >> 5;                 // 32 blocks per batch
    {
        const float* base = x + (size_t)row * D_;
        float acc = 0.f;
#pragma unroll
        for (int k = 0; k < 4; ++k) {
            const int idx = k * 256 + lane * 4;       // coalesced 1KB/wave/iter
            float4 v = *(const float4*)(base + idx);
            float4 w = *(const float4*)(wx + idx);
            acc += v.x * w.x + v.y * w.y + v.z * w.z + v.w * w.w;
        }
#pragma unroll
        for (int off = 32; off > 0; off >>= 1)
            acc += __shfl_down(acc, off, 64);
        if (lane == 0) xs[row] = acc;
    }

    __shared__ int s_last;
    __syncthreads();   // compiler drains vmcnt(0) before s_barrier -> all 4
                       // waves' xs stores are complete before the fence below
    if (threadIdx.x == 0) {
        __threadfence();                              // release xs device-wide
        s_last = (atomicAdd(&cnt[b], 1) == 31);       // last block of batch b?
    }
    __syncthreads();
    if (!s_last) return;

    // ---- phase 2: last-arriving block computes batch b's masked suffix LSE
    __threadfence();                                  // acquire other blocks' xs
    __shared__ float sxs[T_];
    __shared__ int   sm[T_];
    __shared__ float sl[T_];
    const int t = threadIdx.x;
    if (t < T_) {
        sxs[t] = xs[b * T_ + t];
        sm[t]  = mask[b * T_ + t];
    }
    __syncthreads();
    for (int off = 64; off > 0; off >>= 1) {
        if (t < off) sm[t] += sm[t + off];
        __syncthreads();
    }
    const int len = sm[0];                            // guaranteed >= 3

    float loss = 0.f;
    if (t < T_ && t <= len - 3) {
        const int p0 = t + 2;
        float m = sxs[p0];
        for (int p = p0 + 1; p < len; ++p) m = fmaxf(m, sxs[p]);
        float s = 0.f;
        for (int p = p0; p < len; ++p) s += __expf(sxs[p] - m);
        loss = m + __logf(s) - sxs[p0];
    }
    if (t < T_) sl[t] = loss;
    __syncthreads();
    for (int off = 64; off > 0; off >>= 1) {
        if (t < off) sl[t] += sl[t + off];
        __syncthreads();
    }

    __shared__ int s_fin;
    if (t == 0) {
        ploss[b] = sl[0];
        pcnt[b]  = len - 2;
        __threadfence();                              // release partials
        s_fin = (atomicAdd(&cnt[B_], 1) == B_ - 1);   // last batch overall?
    }
    __syncthreads();
    if (!s_fin) return;

    // ---- phase 3: very last block reduces the 64 partials + divides -------
    __threadfence();                                  // acquire partials
    if (t < 64) {
        float l = ploss[t];
        float c = (float)pcnt[t];
#pragma unroll
        for (int off = 32; off > 0; off >>= 1) {
            l += __shfl_down(l, off, 64);
            c += __shfl_down(c, off, 64);
        }
        if (t == 0) out[0] = l / c;                   // cnt >= 64 always (>0)
    }
}

extern "C" void kernel_launch(void* const* d_in, const int* in_sizes, int n_in,
                              void* d_out, int out_size, void* d_ws, size_t ws_size,
                              hipStream_t stream) {
    // setup_inputs order: encoder_output, mask, W_ih, W_hh, b_ih, b_hh, fc_w, fc_b
    const float* x    = (const float*)d_in[0];
    const int*   mask = (const int*)d_in[1];
    const float* fc_w = (const float*)d_in[6];
    float* out = (float*)d_out;

    // workspace layout
    float* xs    = (float*)d_ws;            // B*T floats
    float* ploss = xs + B_ * T_;            // B floats
    int*   pcnt  = (int*)(ploss + B_);      // B ints
    int*   cnt   = pcnt + B_;               // B+1 ints (batch ctrs + done)

    init_kernel<<<1, 128, 0, stream>>>(cnt);
    fused_kernel<<<(B_ * T_) / 4, 256, 0, stream>>>(x, mask, fc_w, xs, ploss,
                                                    pcnt, cnt, out);
}

// Round 2
// 113.370 us; speedup vs baseline: 1.5619x; 1.5619x over previous
//
#include <hip/hip_runtime.h>

// Problem constants (from reference): B=64, T=128, D=1024, H=512
#define B_ 64
#define T_ 128
#define D_ 1024
#define H_ 512

// ---------------------------------------------------------------------------
// Analytic reduction (verified, absmax == 0):
//   loss_row(b,j) = LSE_p(xs[b,p] for p in [j+2, len_b)) - xs[b, j+2]
// (hs, fc_b, W_ih/W_hh/b_* all cancel in lse - logits[..., 0]).
// Only xs[b,t] = dot(x[b,t,:], fc_w[H:]) is needed.
//
// Round-1 lesson: __threadfence() (agent fence for ORDINARY stores) emits
// buffer_wbl2/buffer_inv -> thousands of serialized whole-L2 writebacks ->
// 124 us. Fix: move ALL cross-block handoff data through agent-scope
// relaxed ATOMIC stores/loads (single sc1-flagged instructions that bypass
// the non-coherent L2 and hit the coherent point). Ordering: s_waitcnt
// vmcnt(0) before each signal atomicAdd (the __syncthreads before phase-1's
// signal already drains vmcnt; phase-3's writer gets an explicit asm drain).
// No cache-maintenance instructions anywhere.
// ---------------------------------------------------------------------------

// Zero the B_ per-batch completion counters + 1 grid "done" counter.
__global__ __launch_bounds__(128) void init_kernel(int* __restrict__ cnt) {
    if (threadIdx.x < B_ + 1) cnt[threadIdx.x] = 0;
}

__global__ __launch_bounds__(256) void fused_kernel(
        const float* __restrict__ x, const int* __restrict__ mask,
        const float* __restrict__ fc_w, float* __restrict__ xs,
        float* __restrict__ ploss, int* __restrict__ pcnt,
        int* __restrict__ cnt, float* __restrict__ out)
{
    // ---- phase 1: xs[row] = dot(x[row,:], w_x); 4 rows (waves) per block --
    const float* wx = fc_w + H_;
    const int wave = threadIdx.x >> 6;
    const int lane = threadIdx.x & 63;
    const int row  = blockIdx.x * 4 + wave;           // row in [0, B*T)
    const int b    = blockIdx.x >> 5;                 // 32 blocks per batch
    {
        const float* base = x + (size_t)row * D_;
        float acc = 0.f;
#pragma unroll
        for (int k = 0; k < 4; ++k) {
            const int idx = k * 256 + lane * 4;       // coalesced 1KB/wave/iter
            float4 v = *(const float4*)(base + idx);
            float4 w = *(const float4*)(wx + idx);
            acc += v.x * w.x + v.y * w.y + v.z * w.z + v.w * w.w;
        }
#pragma unroll
        for (int off = 32; off > 0; off >>= 1)
            acc += __shfl_down(acc, off, 64);
        // agent-scope relaxed atomic store: bypasses non-coherent L2 (sc1),
        // lands at the coherent point. No fence needed.
        if (lane == 0)
            __hip_atomic_store(&xs[row], acc, __ATOMIC_RELAXED,
                               __HIP_MEMORY_SCOPE_AGENT);
    }

    __shared__ int s_last;
    __syncthreads();   // compiler drains vmcnt(0) before s_barrier -> all 4
                       // waves' sc1 xs stores are at the coherent point
    if (threadIdx.x == 0) {
        s_last = (__hip_atomic_fetch_add(&cnt[b], 1, __ATOMIC_RELAXED,
                                         __HIP_MEMORY_SCOPE_AGENT) == 31);
    }
    __syncthreads();
    if (!s_last) return;

    // ---- phase 2: last-arriving block computes batch b's masked suffix LSE
    __shared__ float sxs[T_];
    __shared__ int   sm[T_];
    __shared__ float sl[T_];
    const int t = threadIdx.x;
    if (t < T_) {
        // agent-scope relaxed atomic load: reads the coherent point (sc1),
        // cannot see a stale L2 copy.
        sxs[t] = __hip_atomic_load(&xs[b * T_ + t], __ATOMIC_RELAXED,
                                   __HIP_MEMORY_SCOPE_AGENT);
        sm[t]  = mask[b * T_ + t];                    // read-only input: plain
    }
    __syncthreads();
    for (int off = 64; off > 0; off >>= 1) {
        if (t < off) sm[t] += sm[t + off];
        __syncthreads();
    }
    const int len = sm[0];                            // guaranteed >= 3

    float loss = 0.f;
    if (t < T_ && t <= len - 3) {
        const int p0 = t + 2;
        float m = sxs[p0];
        for (int p = p0 + 1; p < len; ++p) m = fmaxf(m, sxs[p]);
        float s = 0.f;
        for (int p = p0; p < len; ++p) s += __expf(sxs[p] - m);
        loss = m + __logf(s) - sxs[p0];
    }
    if (t < T_) sl[t] = loss;
    __syncthreads();
    for (int off = 64; off > 0; off >>= 1) {
        if (t < off) sl[t] += sl[t + off];
        __syncthreads();
    }

    __shared__ int s_fin;
    if (t == 0) {
        __hip_atomic_store(&ploss[b], sl[0], __ATOMIC_RELAXED,
                           __HIP_MEMORY_SCOPE_AGENT);
        __hip_atomic_store(&pcnt[b], len - 2, __ATOMIC_RELAXED,
                           __HIP_MEMORY_SCOPE_AGENT);
        // drain the two sc1 stores to the coherent point BEFORE signalling
        asm volatile("s_waitcnt vmcnt(0)" ::: "memory");
        s_fin = (__hip_atomic_fetch_add(&cnt[B_], 1, __ATOMIC_RELAXED,
                                        __HIP_MEMORY_SCOPE_AGENT) == B_ - 1);
    }
    __syncthreads();
    if (!s_fin) return;

    // ---- phase 3: very last block reduces the 64 partials + divides -------
    if (t < 64) {
        float l = __hip_atomic_load(&ploss[t], __ATOMIC_RELAXED,
                                    __HIP_MEMORY_SCOPE_AGENT);
        float c = (float)__hip_atomic_load(&pcnt[t], __ATOMIC_RELAXED,
                                           __HIP_MEMORY_SCOPE_AGENT);
#pragma unroll
        for (int off = 32; off > 0; off >>= 1) {
            l += __shfl_down(l, off, 64);
            c += __shfl_down(c, off, 64);
        }
        if (t == 0) out[0] = l / c;                   // cnt >= 64 always (>0)
    }
}

extern "C" void kernel_launch(void* const* d_in, const int* in_sizes, int n_in,
                              void* d_out, int out_size, void* d_ws, size_t ws_size,
                              hipStream_t stream) {
    // setup_inputs order: encoder_output, mask, W_ih, W_hh, b_ih, b_hh, fc_w, fc_b
    const float* x    = (const float*)d_in[0];
    const int*   mask = (const int*)d_in[1];
    const float* fc_w = (const float*)d_in[6];
    float* out = (float*)d_out;

    // workspace layout
    float* xs    = (float*)d_ws;            // B*T floats
    float* ploss = xs + B_ * T_;            // B floats
    int*   pcnt  = (int*)(ploss + B_);      // B ints
    int*   cnt   = pcnt + B_;               // B+1 ints (batch ctrs + done)

    init_kernel<<<1, 128, 0, stream>>>(cnt);
    fused_kernel<<<(B_ * T_) / 4, 256, 0, stream>>>(x, mask, fc_w, xs, ploss,
                                                    pcnt, cnt, out);
}

// Round 3
// 104.369 us; speedup vs baseline: 1.6966x; 1.0862x over previous
//
#include <hip/hip_runtime.h>

// Problem constants (from reference): B=64, T=128, D=1024, H=512
#define B_ 64
#define T_ 128
#define D_ 1024
#define H_ 512

#define ROWS_PER_BLOCK 16     // 1024 threads = 16 waves, 1 row per wave
#define BLOCKS_PER_B   (T_ / ROWS_PER_BLOCK)          // 8
#define NBLOCKS        (B_ * BLOCKS_PER_B)            // 512
#define CSTRIDE        32     // ints; 128 B between counters (own cache line)

// ---------------------------------------------------------------------------
// Analytic reduction (verified, absmax == 0):
//   loss_row(b,j) = LSE_p(xs[b,p] for p in [j+2, len_b)) - xs[b, j+2]
// (hs, fc_b, W_ih/W_hh/b_* all cancel in lse - logits[..., 0]).
// Only xs[b,t] = dot(x[b,t,:], fc_w[H:]) is needed.
//
// Round-1 lesson: __threadfence() emits buffer_wbl2/inv -> 124 us. Use
// agent-scope relaxed atomics (sc1, bypass non-coherent L2) instead.
// Round-2 lesson: 2048 far atomicAdds on 65 CONSECUTIVE counter words
// serialize per-line at the coherent point (~14 us). Fix: pad each counter
// to its own 128 B line and cut atomics 4x via 1024-thread blocks.
// ---------------------------------------------------------------------------

// Zero the padded per-batch counters + the grid "done" counter.
__global__ __launch_bounds__(128) void init_kernel(int* __restrict__ cnt) {
    if (threadIdx.x < B_ + 1) cnt[threadIdx.x * CSTRIDE] = 0;
}

__global__ __launch_bounds__(1024) void fused_kernel(
        const float* __restrict__ x, const int* __restrict__ mask,
        const float* __restrict__ fc_w, float* __restrict__ xs,
        float* __restrict__ ploss, int* __restrict__ pcnt,
        int* __restrict__ cnt, float* __restrict__ out)
{
    // ---- phase 1: xs[row] = dot(x[row,:], w_x); 16 rows (waves) per block -
    const float* wx = fc_w + H_;
    const int wave = threadIdx.x >> 6;
    const int lane = threadIdx.x & 63;
    const int row  = blockIdx.x * ROWS_PER_BLOCK + wave;   // row in [0, B*T)
    const int b    = blockIdx.x / BLOCKS_PER_B;            // 8 blocks per batch
    {
        const float* base = x + (size_t)row * D_;
        float acc = 0.f;
#pragma unroll
        for (int k = 0; k < 4; ++k) {
            const int idx = k * 256 + lane * 4;       // coalesced 1KB/wave/iter
            float4 v = *(const float4*)(base + idx);
            float4 w = *(const float4*)(wx + idx);
            acc += v.x * w.x + v.y * w.y + v.z * w.z + v.w * w.w;
        }
#pragma unroll
        for (int off = 32; off > 0; off >>= 1)
            acc += __shfl_down(acc, off, 64);
        // agent-scope relaxed atomic store: sc1 bypasses non-coherent L2.
        if (lane == 0)
            __hip_atomic_store(&xs[row], acc, __ATOMIC_RELAXED,
                               __HIP_MEMORY_SCOPE_AGENT);
    }

    __shared__ int s_last;
    __syncthreads();   // drains vmcnt(0) -> all 16 waves' sc1 stores visible
    if (threadIdx.x == 0) {
        s_last = (__hip_atomic_fetch_add(&cnt[b * CSTRIDE], 1,
                                         __ATOMIC_RELAXED,
                                         __HIP_MEMORY_SCOPE_AGENT)
                  == BLOCKS_PER_B - 1);
    }
    __syncthreads();
    if (!s_last) return;

    // ---- phase 2: last-arriving block computes batch b's masked suffix LSE
    __shared__ float sxs[T_];
    __shared__ int   sm[T_];
    __shared__ float sl[T_];
    const int t = threadIdx.x;
    if (t < T_) {
        sxs[t] = __hip_atomic_load(&xs[b * T_ + t], __ATOMIC_RELAXED,
                                   __HIP_MEMORY_SCOPE_AGENT);
        sm[t]  = mask[b * T_ + t];                    // read-only input: plain
    }
    __syncthreads();
    for (int off = 64; off > 0; off >>= 1) {
        if (t < off) sm[t] += sm[t + off];
        __syncthreads();
    }
    const int len = sm[0];                            // guaranteed >= 3

    float loss = 0.f;
    if (t < T_ && t <= len - 3) {
        const int p0 = t + 2;
        float m = sxs[p0];
        for (int p = p0 + 1; p < len; ++p) m = fmaxf(m, sxs[p]);
        float s = 0.f;
        for (int p = p0; p < len; ++p) s += __expf(sxs[p] - m);
        loss = m + __logf(s) - sxs[p0];
    }
    if (t < T_) sl[t] = loss;
    __syncthreads();
    for (int off = 64; off > 0; off >>= 1) {
        if (t < off) sl[t] += sl[t + off];
        __syncthreads();
    }

    __shared__ int s_fin;
    if (t == 0) {
        __hip_atomic_store(&ploss[b], sl[0], __ATOMIC_RELAXED,
                           __HIP_MEMORY_SCOPE_AGENT);
        __hip_atomic_store(&pcnt[b], len - 2, __ATOMIC_RELAXED,
                           __HIP_MEMORY_SCOPE_AGENT);
        // drain the two sc1 stores to the coherent point BEFORE signalling
        asm volatile("s_waitcnt vmcnt(0)" ::: "memory");
        s_fin = (__hip_atomic_fetch_add(&cnt[B_ * CSTRIDE], 1,
                                        __ATOMIC_RELAXED,
                                        __HIP_MEMORY_SCOPE_AGENT) == B_ - 1);
    }
    __syncthreads();
    if (!s_fin) return;

    // ---- phase 3: very last block reduces the 64 partials + divides -------
    if (t < 64) {
        float l = __hip_atomic_load(&ploss[t], __ATOMIC_RELAXED,
                                    __HIP_MEMORY_SCOPE_AGENT);
        float c = (float)__hip_atomic_load(&pcnt[t], __ATOMIC_RELAXED,
                                           __HIP_MEMORY_SCOPE_AGENT);
#pragma unroll
        for (int off = 32; off > 0; off >>= 1) {
            l += __shfl_down(l, off, 64);
            c += __shfl_down(c, off, 64);
        }
        if (t == 0) out[0] = l / c;                   // cnt >= 64 always (>0)
    }
}

extern "C" void kernel_launch(void* const* d_in, const int* in_sizes, int n_in,
                              void* d_out, int out_size, void* d_ws, size_t ws_size,
                              hipStream_t stream) {
    // setup_inputs order: encoder_output, mask, W_ih, W_hh, b_ih, b_hh, fc_w, fc_b
    const float* x    = (const float*)d_in[0];
    const int*   mask = (const int*)d_in[1];
    const float* fc_w = (const float*)d_in[6];
    float* out = (float*)d_out;

    // workspace layout
    float* xs    = (float*)d_ws;            // B*T floats
    float* ploss = xs + B_ * T_;            // B floats
    int*   pcnt  = (int*)(ploss + B_);      // B ints
    int*   cnt   = pcnt + B_;               // (B+1)*CSTRIDE ints, padded

    init_kernel<<<1, 128, 0, stream>>>(cnt);
    fused_kernel<<<NBLOCKS, 1024, 0, stream>>>(x, mask, fc_w, xs, ploss,
                                               pcnt, cnt, out);
}

// Round 4
// 103.042 us; speedup vs baseline: 1.7185x; 1.0129x over previous
//
#include <hip/hip_runtime.h>

// Problem constants (from reference): B=64, T=128, D=1024, H=512
#define B_ 64
#define T_ 128
#define D_ 1024
#define H_ 512
#define CSTRIDE 32   // ints; 128 B between counters (each on its own line)

// ---------------------------------------------------------------------------
// Analytic reduction (verified, absmax == 0):
//   loss_row(b,j) = LSE_p(xs[b,p] for p in [j+2, len_b)) - xs[b, j+2]
// (hs, fc_b, W_ih/W_hh/b_* all cancel in lse - logits[..., 0]).
// Only xs[b,t] = dot(x[b,t,:], fc_w[H:]) is needed.
//
// Session lessons (R1-R3):
//  - __threadfence() = buffer_wbl2/inv -> 124 us. Never.
//  - In-kernel cross-block handshake (even padded sc1 atomics) costs ~5 us
//    of far-memory latency tail; an on-stream kernel boundary costs ~1-2 us.
//    => dispatch-boundary sync BEATS software fusion for this shape.
// This round: R0's split structure, minus init/final dispatches:
//  - kernel 1 (xs) block 0 also zeroes the counters (visible to kernel 2
//    via stream order — no race, no extra dispatch).
//  - kernel 2 (loss) folds the final reduce into the last-arriving block
//    via a two-level counter tree (8 group ctrs + 1 top, each padded to its
//    own 128 B line -> max 8 serialized same-line atomics per level).
// ---------------------------------------------------------------------------

// Kernel 1: xs[b,t] = dot(x[b,t,:], w_x); one wave per row; also zero ctrs.
__global__ __launch_bounds__(256) void xs_kernel(const float* __restrict__ x,
                                                 const float* __restrict__ fc_w,
                                                 float* __restrict__ xs,
                                                 int* __restrict__ cnt) {
    if (blockIdx.x == 0 && threadIdx.x < 9)   // 8 group ctrs + 1 top ctr
        __hip_atomic_store(&cnt[threadIdx.x * CSTRIDE], 0, __ATOMIC_RELAXED,
                           __HIP_MEMORY_SCOPE_AGENT);
    const float* wx = fc_w + H_;
    const int wave = threadIdx.x >> 6;
    const int lane = threadIdx.x & 63;
    const int row  = blockIdx.x * 4 + wave;          // row in [0, B*T)
    const float* base = x + (size_t)row * D_;
    float acc = 0.f;
#pragma unroll
    for (int k = 0; k < 4; ++k) {
        const int idx = k * 256 + lane * 4;          // coalesced 1KB/wave/iter
        float4 v = *(const float4*)(base + idx);
        float4 w = *(const float4*)(wx + idx);
        acc += v.x * w.x + v.y * w.y + v.z * w.z + v.w * w.w;
    }
#pragma unroll
    for (int off = 32; off > 0; off >>= 1)
        acc += __shfl_down(acc, off, 64);
    if (lane == 0) xs[row] = acc;                    // plain store: kernel
                                                     // boundary publishes it
}

// Kernel 2: per-batch masked suffix LSE; last-arriving block (two-level
// counter tree) also reduces the 64 partials and writes the scalar out.
__global__ __launch_bounds__(128) void loss_kernel(const int* __restrict__ mask,
                                                   const float* __restrict__ xs,
                                                   float* __restrict__ ploss,
                                                   int* __restrict__ pcnt,
                                                   int* __restrict__ cnt,
                                                   float* __restrict__ out) {
    __shared__ float sxs[T_];
    __shared__ int   sm[T_];
    __shared__ float sl[T_];
    const int b = blockIdx.x;
    const int t = threadIdx.x;
    sxs[t] = xs[b * T_ + t];                         // plain load (stream order)
    sm[t]  = mask[b * T_ + t];
    __syncthreads();
    for (int off = 64; off > 0; off >>= 1) {
        if (t < off) sm[t] += sm[t + off];
        __syncthreads();
    }
    const int len = sm[0];                           // guaranteed >= 3

    float loss = 0.f;
    if (t <= len - 3) {
        const int p0 = t + 2;
        float m = sxs[p0];
        for (int p = p0 + 1; p < len; ++p) m = fmaxf(m, sxs[p]);
        float s = 0.f;
        for (int p = p0; p < len; ++p) s += __expf(sxs[p] - m);
        loss = m + __logf(s) - sxs[p0];
    }
    sl[t] = loss;
    __syncthreads();
    for (int off = 64; off > 0; off >>= 1) {
        if (t < off) sl[t] += sl[t + off];
        __syncthreads();
    }

    // publish partials (sc1 -> coherent point), then two-level signal
    __shared__ int s_fin;
    if (t == 0) {
        __hip_atomic_store(&ploss[b], sl[0], __ATOMIC_RELAXED,
                           __HIP_MEMORY_SCOPE_AGENT);
        __hip_atomic_store(&pcnt[b], len - 2, __ATOMIC_RELAXED,
                           __HIP_MEMORY_SCOPE_AGENT);
        asm volatile("s_waitcnt vmcnt(0)" ::: "memory");  // drain before signal
        s_fin = 0;
        // level 1: 8 blocks per group counter (max 8 serialized same-line ops)
        if (__hip_atomic_fetch_add(&cnt[(b >> 3) * CSTRIDE], 1,
                                   __ATOMIC_RELAXED,
                                   __HIP_MEMORY_SCOPE_AGENT) == 7) {
            // level 2: 8 group-last blocks race on the top counter
            if (__hip_atomic_fetch_add(&cnt[8 * CSTRIDE], 1,
                                       __ATOMIC_RELAXED,
                                       __HIP_MEMORY_SCOPE_AGENT) == 7)
                s_fin = 1;
        }
    }
    __syncthreads();
    if (!s_fin) return;

    // very last block: reduce the 64 partials (same order as before) + divide
    if (t < 64) {
        float l = __hip_atomic_load(&ploss[t], __ATOMIC_RELAXED,
                                    __HIP_MEMORY_SCOPE_AGENT);
        float c = (float)__hip_atomic_load(&pcnt[t], __ATOMIC_RELAXED,
                                           __HIP_MEMORY_SCOPE_AGENT);
#pragma unroll
        for (int off = 32; off > 0; off >>= 1) {
            l += __shfl_down(l, off, 64);
            c += __shfl_down(c, off, 64);
        }
        if (t == 0) out[0] = l / c;                  // cnt >= 64 always (>0)
    }
}

extern "C" void kernel_launch(void* const* d_in, const int* in_sizes, int n_in,
                              void* d_out, int out_size, void* d_ws, size_t ws_size,
                              hipStream_t stream) {
    // setup_inputs order: encoder_output, mask, W_ih, W_hh, b_ih, b_hh, fc_w, fc_b
    const float* x    = (const float*)d_in[0];
    const int*   mask = (const int*)d_in[1];
    const float* fc_w = (const float*)d_in[6];
    float* out = (float*)d_out;

    // workspace layout
    float* xs    = (float*)d_ws;            // B*T floats
    float* ploss = xs + B_ * T_;            // B floats
    int*   pcnt  = (int*)(ploss + B_);      // B ints
    int*   cnt   = pcnt + B_;               // 9*CSTRIDE ints (8 group + 1 top)

    xs_kernel<<<(B_ * T_) / 4, 256, 0, stream>>>(x, fc_w, xs, cnt);
    loss_kernel<<<B_, 128, 0, stream>>>(mask, xs, ploss, pcnt, cnt, out);
}